// Round 13
// baseline (221.927 us; speedup 1.0000x reference)
//
#include <hip/hip_runtime.h>

// NoMCOutModel round 27: r26 + parallel K-half scan MFMAs (+ w15 pressure
// reorder). r26 post-mortem: 172.8 -> 150.3 (J-under-scan + barrier cut
// landed in full ~= J was fully hidden -> post-B window is scan-bound).
// WRITE 72KB -> 4.2MB = ~4-VGPR once-per-it spill on w15 (8 b-frags + A +
// pack chain at the 64-VGPR wall).
// This round, scan only: MFMA is linear in C, so the 2-deep serial chain
// acc=MFMA(A1,b1,MFMA(A0,b0,mi)) splits into two INDEPENDENT MFMAs
// s1=MFMA(A0,b0,{mi}), s2=MFMA(A1,b1,{0}), c=s1[0]+s2[0] -- one MFMA
// latency + 2cy add instead of two chained latencies (~95 -> ~75 cy/step).
// kt chains processed in 2 batches (0,1 then 2,3) with b-frag loads split
// the same way: peak live b-frags 32->16 VGPR, attacking the spill.
// Numerics: +1 fp32 add reorder per output (~1ulp) vs in-MFMA chaining.
// Everything outside the scan MFMA section is byte-identical to r26.

namespace {

constexpr int B_ = 256, T_ = 256, M_ = 8, AUX_ = 32, H_ = 64;
constexpr int NTILE = 288;               // (64*64 + 8*64)/16 logit col-tiles
constexpr float LOG2E = 1.4426950408889634f;

typedef __fp16 f16x2 __attribute__((ext_vector_type(2)));
typedef __fp16 f16x8 __attribute__((ext_vector_type(8)));
typedef float  f32x4 __attribute__((ext_vector_type(4)));
typedef int    i32x4 __attribute__((ext_vector_type(4)));

union V8 { f16x8 v; f16x2 p[4]; i32x4 i; };

#if __has_builtin(__builtin_amdgcn_exp2f)
#define EXP2(x) __builtin_amdgcn_exp2f(x)
#else
#define EXP2(x) exp2f(x)
#endif

#define MFMA16(A, Bv, C) __builtin_amdgcn_mfma_f32_16x16x32_f16((A), (Bv), (C), 0, 0, 0)

__device__ __forceinline__ float dot2(f16x2 a, f16x2 b, float c) {
    return __builtin_amdgcn_fdot2(a, b, c, false);
}

template <int CTRL>
__device__ __forceinline__ float dpp_add(float v) {
    int t = __builtin_amdgcn_update_dpp(0, __builtin_bit_cast(int, v),
                                        CTRL, 0xf, 0xf, true);
    return v + __builtin_bit_cast(float, t);
}
__device__ __forceinline__ float sum16_all(float v) {
    v = dpp_add<0xB1>(v);   // quad_perm [1,0,3,2]
    v = dpp_add<0x4E>(v);   // quad_perm [2,3,0,1]
    v = dpp_add<0x141>(v);  // row_half_mirror
    v = dpp_add<0x140>(v);  // row_mirror
    return v;
}
__device__ __forceinline__ float sum64_uni(float v) {
    v = dpp_add<0x111>(v); v = dpp_add<0x112>(v); v = dpp_add<0x114>(v);
    v = dpp_add<0x118>(v); v = dpp_add<0x142>(v); v = dpp_add<0x143>(v);
    return __builtin_bit_cast(float,
        __builtin_amdgcn_readlane(__builtin_bit_cast(int, v), 63));
}

// RNE pair-pack: every lane ends with (f16(chat[2P]), f16(chat[2P+1])) where
// P = lane>>1. Own value is converted RNE ((__fp16) cast = v_cvt_f16_f32),
// then quad_perm DPP broadcasts the even/odd pair members to both lanes.
__device__ __forceinline__ int pack_pair_rne(float v) {
    const int hv = (int)__builtin_bit_cast(unsigned short, (__fp16)v);
    const int ev = __builtin_amdgcn_update_dpp(0, hv, 0xA0, 0xf, 0xf, true); // [0,0,2,2]
    const int ov = __builtin_amdgcn_update_dpp(0, hv, 0xF5, 0xf, 0xf, true); // [1,1,3,3]
    return ev | (ov << 16);
}

#define LDS_FENCE() __asm__ volatile("s_waitcnt lgkmcnt(0)" ::: "memory")

// ---------------- prep: W -> f16 MFMA B-frag layout in ws ----------------
// ws[gt*1024 + lane*16] : f16x8 frag, B[k = (lane>>4)*8 + j][n = gt*16+(lane&15)]
// ws + 288*1024 : float bias[4608] (log2e-scaled)
__global__ __launch_bounds__(64)
void nomc_prep(const float* __restrict__ Wj, const float* __restrict__ bj,
               const float* __restrict__ Wr, const float* __restrict__ br,
               void* __restrict__ ws)
{
    const int gt = blockIdx.x;           // 0..287
    const int l = threadIdx.x, q = l >> 4, l15 = l & 15;
    const float* src; const float* bsrc; int stride;
    if (gt < 256) { const int n = gt * 16 + l15;        src = Wr + n; bsrc = br + n; stride = 4096; }
    else          { const int n = (gt - 256) * 16 + l15; src = Wj + n; bsrc = bj + n; stride = 512; }
    V8 v;
#pragma unroll
    for (int j = 0; j < 4; ++j) {
        const float f0 = src[(q * 8 + 2 * j)     * stride] * LOG2E;
        const float f1 = src[(q * 8 + 2 * j + 1) * stride] * LOG2E;
        v.p[j] = __builtin_amdgcn_cvt_pkrtz(f0, f1);
    }
    *(i32x4*)((char*)ws + (size_t)gt * 1024 + l * 16) = v.i;
    if (l < 16)
        ((float*)((char*)ws + NTILE * 1024))[gt * 16 + l] = bsrc[0] * LOG2E;
}

// A-frag staging for timestep block ITN
#define AF_LOAD(ITN)                                                         \
    do {                                                                     \
        const float* xa_ = x_a + ((size_t)b * T_ + (ITN) * 16 + l15) * AUX_ + q * 8; \
        const f32x4 x0_ = *(const f32x4*)xa_;                                \
        const f32x4 x1_ = *(const f32x4*)(xa_ + 4);                          \
        af.p[0] = __builtin_amdgcn_cvt_pkrtz(x0_.x, x0_.y);                  \
        af.p[1] = __builtin_amdgcn_cvt_pkrtz(x0_.z, x0_.w);                  \
        af.p[2] = __builtin_amdgcn_cvt_pkrtz(x1_.x, x1_.y);                  \
        af.p[3] = __builtin_amdgcn_cvt_pkrtz(x1_.z, x1_.w);                  \
    } while (0)

// waves 0..7: full J group w (4 tiles, JIT loads) -> JT + xj[.][w] direct
#define J_GROUP(ITN)                                                         \
    do {                                                                     \
        float ej0 = 0.f, ej1 = 0.f, ej2 = 0.f, ej3 = 0.f;                    \
        const int mp = w ^ sx;                                               \
        _Pragma("unroll")                                                    \
        for (int tt = 0; tt < 4; ++tt) {                                     \
            const int gt = (64 + w) * 4 + tt;                                \
            V8 bf; bf.i = *(const i32x4*)(wsb + (size_t)gt * 1024 + l * 16); \
            const float bv = wbias[gt * 16 + l15];                           \
            f32x4 acc = {bv, bv, bv, bv};                                    \
            acc = MFMA16(af.v, bf.v, acc);                                   \
            const float e0 = EXP2(acc[0]), e1 = EXP2(acc[1]);                \
            const float e2 = EXP2(acc[2]), e3 = EXP2(acc[3]);                \
            const int kk = (tt << 4) + l15;                                  \
            JT[q * 4 + 0][kk][mp] = (__fp16)e0;                              \
            JT[q * 4 + 1][kk][mp] = (__fp16)e1;                              \
            JT[q * 4 + 2][kk][mp] = (__fp16)e2;                              \
            JT[q * 4 + 3][kk][mp] = (__fp16)e3;                              \
            ej0 += e0; ej1 += e1; ej2 += e2; ej3 += e3;                      \
        }                                                                    \
        ej0 = sum16_all(ej0); ej1 = sum16_all(ej1);                          \
        ej2 = sum16_all(ej2); ej3 = sum16_all(ej3);                          \
        if (l15 == 0) {                                                      \
            xj[q * 4 + 0][mp] = (__fp16)(xm_lds[(ITN) * 16 + q * 4 + 0][w] * __builtin_amdgcn_rcpf(ej0)); \
            xj[q * 4 + 1][mp] = (__fp16)(xm_lds[(ITN) * 16 + q * 4 + 1][w] * __builtin_amdgcn_rcpf(ej1)); \
            xj[q * 4 + 2][mp] = (__fp16)(xm_lds[(ITN) * 16 + q * 4 + 2][w] * __builtin_amdgcn_rcpf(ej2)); \
            xj[q * 4 + 3][mp] = (__fp16)(xm_lds[(ITN) * 16 + q * 4 + 3][w] * __builtin_amdgcn_rcpf(ej3)); \
        }                                                                    \
    } while (0)

// ---------------- main ----------------
__global__ __launch_bounds__(1024, 4)
void nomc_main(const float* __restrict__ x_m, const float* __restrict__ x_a,
               const float* __restrict__ Wo, const float* __restrict__ bo,
               const float* __restrict__ Wfc, const float* __restrict__ bfc,
               const void* __restrict__ ws, float* __restrict__ out)
{
    const int b = blockIdx.x, tid = threadIdx.x;
    const int w = tid >> 6, l = tid & 63, q = l >> 4, l15 = l & 15;

    __shared__ __align__(16) __fp16 RT[16][8][64][8];   // 131072 B  RT[t][h>>3][k][(h&7)^((t>>2)<<1)]=e
    __shared__ __align__(16) __fp16 JT[16][64][8];      //  16384 B  JT[t][k][m^((t>>2)<<1)]=e_j
    __shared__ float sinv[16][64];                      //   4096 B  1/rowsum(R)
    __shared__ __align__(16) __fp16 xj[16][8];          //    256 B  [t][m^((t>>2)<<1)]=xm/s_j
    __shared__ __align__(16) __fp16 minL[16][64];       //   2048 B  m_in[t][k]
    __shared__ float xm_lds[T_][M_];                    //   8192 B
    __shared__ float cfin_lds[H_];                      //    256 B
    // total 162304 <= 163840

    {   // stage x_m once
        const float* xmb = x_m + (size_t)b * T_ * M_;
        for (int i = tid; i < T_ * M_; i += 1024) (&xm_lds[0][0])[i] = xmb[i];
    }
    __syncthreads();

    const char* wsb = (const char*)ws;
    const float* wbias = (const float*)(wsb + NTILE * 1024);
    const int sx = q << 1;                   // store-side bank swizzle

    V8 af;                                   // A-frag, persists across barriers
    AF_LOAD(0);
    if (w < 8) J_GROUP(0);                   // prologue J(0)
    __syncthreads();                         // JT(0), xj(0) visible

    float c0 = 0.f, c1 = 0.f, c2 = 0.f, c3 = 0.f;   // c[kt*16 + l15], q-replicated

    for (int it = 0; it < 16; ++it) {
        // ====== m_in(it) at it-top: minL[t][k] = xj[t].JT[t][k] ======
        // JT/xj(it) were written during the previous overlap window
        // (visible since barrier D). minL rides barrier B to the scan.
        {
            V8 jv; jv.v = *(const f16x8*)&JT[w][l][0];
            V8 xv; xv.v = *(const f16x8*)&xj[w][0];
            float s = 0.f;
            s = dot2(jv.p[0], xv.p[0], s);
            s = dot2(jv.p[1], xv.p[1], s);
            s = dot2(jv.p[2], xv.p[2], s);
            s = dot2(jv.p[3], xv.p[3], s);
            minL[w][l] = (__fp16)s;
        }

        // ---- 4 R groups per wave, JIT loads (r21's proven codegen) ----
#pragma unroll 1
        for (int g = 0; g < 4; ++g) {
            const int gg = w * 4 + g;                    // 0..63
            float es0 = 0.f, es1 = 0.f, es2 = 0.f, es3 = 0.f;
            const int hb = gg >> 3, p = (gg & 7) ^ sx;   // swizzled slot
#pragma unroll
            for (int tt = 0; tt < 4; ++tt) {
                const int gt = gg * 4 + tt;
                V8 bf; bf.i = *(const i32x4*)(wsb + (size_t)gt * 1024 + l * 16);
                const float bv = wbias[gt * 16 + l15];
                f32x4 acc = {bv, bv, bv, bv};
                acc = MFMA16(af.v, bf.v, acc);
                const float e0 = EXP2(acc[0]), e1 = EXP2(acc[1]);
                const float e2 = EXP2(acc[2]), e3 = EXP2(acc[3]);
                const int kk = (tt << 4) + l15;
                RT[q * 4 + 0][hb][kk][p] = (__fp16)e0;
                RT[q * 4 + 1][hb][kk][p] = (__fp16)e1;
                RT[q * 4 + 2][hb][kk][p] = (__fp16)e2;
                RT[q * 4 + 3][hb][kk][p] = (__fp16)e3;
                es0 += e0; es1 += e1; es2 += e2; es3 += e3;
            }
            const float sr0 = sum16_all(es0), sr1 = sum16_all(es1);
            const float sr2 = sum16_all(es2), sr3 = sum16_all(es3);
            if (l15 == 0) {
                sinv[q * 4 + 0][gg] = __builtin_amdgcn_rcpf(sr0);
                sinv[q * 4 + 1][gg] = __builtin_amdgcn_rcpf(sr1);
                sinv[q * 4 + 2][gg] = __builtin_amdgcn_rcpf(sr2);
                sinv[q * 4 + 3][gg] = __builtin_amdgcn_rcpf(sr3);
            }
        }
        __syncthreads();   // barrier B: RT, sinv, minL visible

        // ============ scan(it) (wave 15) ∥ J(it+1) (waves 0..7) ============
        if (w == 15) {
            const int ab = q << 5;              // A0 byte base = lane 8q
            for (int u = 0; u < 16; ++u) {
                const int sig = (u >> 2) & 3;   // matches producer swizzle
                // ---- c-independent prefetch (no fences -> compiler pipelines) ----
                const float mi0 = (float)minL[u][l15];
                const float mi1 = (float)minL[u][16 + l15];
                const float mi2 = (float)minL[u][32 + l15];
                const float mi3 = (float)minL[u][48 + l15];
                const float svl = sinv[u][l];
                // ---- chat_l = c[l] * sinv[u][l]  (in-reg, RNE) ----
                const float cown = (q == 0) ? c0 : (q == 1) ? c1 : (q == 2) ? c2 : c3;
                const int spk = pack_pair_rne(cown * svl);  // lane pair 2P,2P+1 -> chat pair P
                // ---- A-frags via bpermute: A0 pair jp <- lane 8q+2(jp^sig);
                //      A1 pair jp <- lane 32+8q+2(jp^sig) (offset 128 folds) ----
                V8 A0f, A1f;
                A0f.i[0] = __builtin_amdgcn_ds_bpermute(ab + ((0 ^ sig) << 3), spk);
                A0f.i[1] = __builtin_amdgcn_ds_bpermute(ab + ((1 ^ sig) << 3), spk);
                A0f.i[2] = __builtin_amdgcn_ds_bpermute(ab + ((2 ^ sig) << 3), spk);
                A0f.i[3] = __builtin_amdgcn_ds_bpermute(ab + ((3 ^ sig) << 3), spk);
                A1f.i[0] = __builtin_amdgcn_ds_bpermute(128 + ab + ((0 ^ sig) << 3), spk);
                A1f.i[1] = __builtin_amdgcn_ds_bpermute(128 + ab + ((1 ^ sig) << 3), spk);
                A1f.i[2] = __builtin_amdgcn_ds_bpermute(128 + ab + ((2 ^ sig) << 3), spk);
                A1f.i[3] = __builtin_amdgcn_ds_bpermute(128 + ab + ((3 ^ sig) << 3), spk);
                // ---- batch 1: kt chains 0,1 -- parallel K-halves, add after ----
                {
                    V8 b00, b01, b10, b11;
                    b00.v = *(const f16x8*)&RT[u][q][l15][0];
                    b01.v = *(const f16x8*)&RT[u][4 + q][l15][0];
                    b10.v = *(const f16x8*)&RT[u][q][16 + l15][0];
                    b11.v = *(const f16x8*)&RT[u][4 + q][16 + l15][0];
                    f32x4 a0 = {mi0, mi0, mi0, mi0};
                    f32x4 a0b = {0.f, 0.f, 0.f, 0.f};
                    f32x4 a1 = {mi1, mi1, mi1, mi1};
                    f32x4 a1b = {0.f, 0.f, 0.f, 0.f};
                    a0  = MFMA16(A0f.v, b00.v, a0);
                    a0b = MFMA16(A1f.v, b01.v, a0b);
                    a1  = MFMA16(A0f.v, b10.v, a1);
                    a1b = MFMA16(A1f.v, b11.v, a1b);
                    c0 = a0[0] + a0b[0];
                    c1 = a1[0] + a1b[0];
                }
                // ---- batch 2: kt chains 2,3 ----
                {
                    V8 b20, b21, b30, b31;
                    b20.v = *(const f16x8*)&RT[u][q][32 + l15][0];
                    b21.v = *(const f16x8*)&RT[u][4 + q][32 + l15][0];
                    b30.v = *(const f16x8*)&RT[u][q][48 + l15][0];
                    b31.v = *(const f16x8*)&RT[u][4 + q][48 + l15][0];
                    f32x4 a2 = {mi2, mi2, mi2, mi2};
                    f32x4 a2b = {0.f, 0.f, 0.f, 0.f};
                    f32x4 a3 = {mi3, mi3, mi3, mi3};
                    f32x4 a3b = {0.f, 0.f, 0.f, 0.f};
                    a2  = MFMA16(A0f.v, b20.v, a2);
                    a2b = MFMA16(A1f.v, b21.v, a2b);
                    a3  = MFMA16(A0f.v, b30.v, a3);
                    a3b = MFMA16(A1f.v, b31.v, a3b);
                    c2 = a2[0] + a2b[0];
                    c3 = a3[0] + a3b[0];
                }
            }
            if (it < 15) AF_LOAD(it + 1);
        } else if (it < 15) {
            AF_LOAD(it + 1);                 // af(it+1) for J now, R next it
            if (w < 8) J_GROUP(it + 1);      // JT(it+1) + xj(it+1), hidden
        }
        __syncthreads();   // barrier D
    }

    // ---- epilogue: out = (sigmoid(xa_T@Wo+bo) * c_T) @ Wfc + bfc ----
    if (w == 15) {
        const float cown = (q == 0) ? c0 : (q == 1) ? c1 : (q == 2) ? c2 : c3;
        cfin_lds[l] = cown;                              // all-lane write
        LDS_FENCE();
        const float* xa = x_a + ((size_t)b * T_ + (T_ - 1)) * AUX_;
        float L = bo[l];
#pragma unroll
        for (int a = 0; a < AUX_; ++a) L = fmaf(xa[a], Wo[a * H_ + l], L);
        const float o = 1.0f / (1.0f + __expf(-L));
        const float cfin = cfin_lds[l];
        float p = (o * cfin) * Wfc[l];
        p = sum64_uni(p);
        if (l == 0) out[b] = p + bfc[0];
        out[B_ + b * H_ + l] = cfin;                     // c_final, coalesced
    }
}

} // namespace

extern "C" void kernel_launch(void* const* d_in, const int* in_sizes, int n_in,
                              void* d_out, int out_size, void* d_ws, size_t ws_size,
                              hipStream_t stream) {
    const float* x_m = (const float*)d_in[0];
    const float* x_a = (const float*)d_in[1];
    const float* Wj  = (const float*)d_in[2];
    const float* bj  = (const float*)d_in[3];
    const float* Wr  = (const float*)d_in[4];
    const float* br  = (const float*)d_in[5];
    const float* Wo  = (const float*)d_in[6];
    const float* bo  = (const float*)d_in[7];
    const float* Wfc = (const float*)d_in[8];
    const float* bfc = (const float*)d_in[9];
    float* out = (float*)d_out;

    hipLaunchKernelGGL(nomc_prep, dim3(NTILE), dim3(64), 0, stream,
                       Wj, bj, Wr, br, d_ws);
    hipLaunchKernelGGL(nomc_main, dim3(B_), dim3(1024), 0, stream,
                       x_m, x_a, Wo, bo, Wfc, bfc, d_ws, out);
}

// Round 14
// 213.637 us; speedup vs baseline: 1.0388x; 1.0388x over previous
//
#include <hip/hip_runtime.h>

// NoMCOutModel round 28: REVERT to r26 (session best, 150.3us main).
// r27 post-mortem (+9us): the parallel K-half split was a double mistake:
// (1) chained MFMAs on one accumulator are HW-forwarded -- the "two serial
// latencies" model was wrong, so splitting bought nothing; (2) batching
// the 8 b-frag ds_read_b128 into 2 groups exposed ~1 LDS round-trip
// (~120cy) per scan step x 256 = ~13us on the serial wave. r26's 4.2MB
// scratch spill costs LESS than the ILP lost avoiding it -- keep it.
// Verified-win ledger: store-swizzle +6 (r15), bpermute scan +13 (r18),
// balanced produce +16 (r21), J-under-scan + 2-barrier it +22 (r26).
// Structure: waves 0..7 own full J groups hidden under the w15 scan;
// m_in at it-top; 2 barriers/it; JIT R loads (unroll-1 outer).

namespace {

constexpr int B_ = 256, T_ = 256, M_ = 8, AUX_ = 32, H_ = 64;
constexpr int NTILE = 288;               // (64*64 + 8*64)/16 logit col-tiles
constexpr float LOG2E = 1.4426950408889634f;

typedef __fp16 f16x2 __attribute__((ext_vector_type(2)));
typedef __fp16 f16x8 __attribute__((ext_vector_type(8)));
typedef float  f32x4 __attribute__((ext_vector_type(4)));
typedef int    i32x4 __attribute__((ext_vector_type(4)));

union V8 { f16x8 v; f16x2 p[4]; i32x4 i; };

#if __has_builtin(__builtin_amdgcn_exp2f)
#define EXP2(x) __builtin_amdgcn_exp2f(x)
#else
#define EXP2(x) exp2f(x)
#endif

#define MFMA16(A, Bv, C) __builtin_amdgcn_mfma_f32_16x16x32_f16((A), (Bv), (C), 0, 0, 0)

__device__ __forceinline__ float dot2(f16x2 a, f16x2 b, float c) {
    return __builtin_amdgcn_fdot2(a, b, c, false);
}

template <int CTRL>
__device__ __forceinline__ float dpp_add(float v) {
    int t = __builtin_amdgcn_update_dpp(0, __builtin_bit_cast(int, v),
                                        CTRL, 0xf, 0xf, true);
    return v + __builtin_bit_cast(float, t);
}
__device__ __forceinline__ float sum16_all(float v) {
    v = dpp_add<0xB1>(v);   // quad_perm [1,0,3,2]
    v = dpp_add<0x4E>(v);   // quad_perm [2,3,0,1]
    v = dpp_add<0x141>(v);  // row_half_mirror
    v = dpp_add<0x140>(v);  // row_mirror
    return v;
}
__device__ __forceinline__ float sum64_uni(float v) {
    v = dpp_add<0x111>(v); v = dpp_add<0x112>(v); v = dpp_add<0x114>(v);
    v = dpp_add<0x118>(v); v = dpp_add<0x142>(v); v = dpp_add<0x143>(v);
    return __builtin_bit_cast(float,
        __builtin_amdgcn_readlane(__builtin_bit_cast(int, v), 63));
}

// RNE pair-pack: every lane ends with (f16(chat[2P]), f16(chat[2P+1])) where
// P = lane>>1. Own value is converted RNE ((__fp16) cast = v_cvt_f16_f32),
// then quad_perm DPP broadcasts the even/odd pair members to both lanes.
__device__ __forceinline__ int pack_pair_rne(float v) {
    const int hv = (int)__builtin_bit_cast(unsigned short, (__fp16)v);
    const int ev = __builtin_amdgcn_update_dpp(0, hv, 0xA0, 0xf, 0xf, true); // [0,0,2,2]
    const int ov = __builtin_amdgcn_update_dpp(0, hv, 0xF5, 0xf, 0xf, true); // [1,1,3,3]
    return ev | (ov << 16);
}

#define LDS_FENCE() __asm__ volatile("s_waitcnt lgkmcnt(0)" ::: "memory")

// ---------------- prep: W -> f16 MFMA B-frag layout in ws ----------------
// ws[gt*1024 + lane*16] : f16x8 frag, B[k = (lane>>4)*8 + j][n = gt*16+(lane&15)]
// ws + 288*1024 : float bias[4608] (log2e-scaled)
__global__ __launch_bounds__(64)
void nomc_prep(const float* __restrict__ Wj, const float* __restrict__ bj,
               const float* __restrict__ Wr, const float* __restrict__ br,
               void* __restrict__ ws)
{
    const int gt = blockIdx.x;           // 0..287
    const int l = threadIdx.x, q = l >> 4, l15 = l & 15;
    const float* src; const float* bsrc; int stride;
    if (gt < 256) { const int n = gt * 16 + l15;        src = Wr + n; bsrc = br + n; stride = 4096; }
    else          { const int n = (gt - 256) * 16 + l15; src = Wj + n; bsrc = bj + n; stride = 512; }
    V8 v;
#pragma unroll
    for (int j = 0; j < 4; ++j) {
        const float f0 = src[(q * 8 + 2 * j)     * stride] * LOG2E;
        const float f1 = src[(q * 8 + 2 * j + 1) * stride] * LOG2E;
        v.p[j] = __builtin_amdgcn_cvt_pkrtz(f0, f1);
    }
    *(i32x4*)((char*)ws + (size_t)gt * 1024 + l * 16) = v.i;
    if (l < 16)
        ((float*)((char*)ws + NTILE * 1024))[gt * 16 + l] = bsrc[0] * LOG2E;
}

// A-frag staging for timestep block ITN
#define AF_LOAD(ITN)                                                         \
    do {                                                                     \
        const float* xa_ = x_a + ((size_t)b * T_ + (ITN) * 16 + l15) * AUX_ + q * 8; \
        const f32x4 x0_ = *(const f32x4*)xa_;                                \
        const f32x4 x1_ = *(const f32x4*)(xa_ + 4);                          \
        af.p[0] = __builtin_amdgcn_cvt_pkrtz(x0_.x, x0_.y);                  \
        af.p[1] = __builtin_amdgcn_cvt_pkrtz(x0_.z, x0_.w);                  \
        af.p[2] = __builtin_amdgcn_cvt_pkrtz(x1_.x, x1_.y);                  \
        af.p[3] = __builtin_amdgcn_cvt_pkrtz(x1_.z, x1_.w);                  \
    } while (0)

// waves 0..7: full J group w (4 tiles, JIT loads) -> JT + xj[.][w] direct
#define J_GROUP(ITN)                                                         \
    do {                                                                     \
        float ej0 = 0.f, ej1 = 0.f, ej2 = 0.f, ej3 = 0.f;                    \
        const int mp = w ^ sx;                                               \
        _Pragma("unroll")                                                    \
        for (int tt = 0; tt < 4; ++tt) {                                     \
            const int gt = (64 + w) * 4 + tt;                                \
            V8 bf; bf.i = *(const i32x4*)(wsb + (size_t)gt * 1024 + l * 16); \
            const float bv = wbias[gt * 16 + l15];                           \
            f32x4 acc = {bv, bv, bv, bv};                                    \
            acc = MFMA16(af.v, bf.v, acc);                                   \
            const float e0 = EXP2(acc[0]), e1 = EXP2(acc[1]);                \
            const float e2 = EXP2(acc[2]), e3 = EXP2(acc[3]);                \
            const int kk = (tt << 4) + l15;                                  \
            JT[q * 4 + 0][kk][mp] = (__fp16)e0;                              \
            JT[q * 4 + 1][kk][mp] = (__fp16)e1;                              \
            JT[q * 4 + 2][kk][mp] = (__fp16)e2;                              \
            JT[q * 4 + 3][kk][mp] = (__fp16)e3;                              \
            ej0 += e0; ej1 += e1; ej2 += e2; ej3 += e3;                      \
        }                                                                    \
        ej0 = sum16_all(ej0); ej1 = sum16_all(ej1);                          \
        ej2 = sum16_all(ej2); ej3 = sum16_all(ej3);                          \
        if (l15 == 0) {                                                      \
            xj[q * 4 + 0][mp] = (__fp16)(xm_lds[(ITN) * 16 + q * 4 + 0][w] * __builtin_amdgcn_rcpf(ej0)); \
            xj[q * 4 + 1][mp] = (__fp16)(xm_lds[(ITN) * 16 + q * 4 + 1][w] * __builtin_amdgcn_rcpf(ej1)); \
            xj[q * 4 + 2][mp] = (__fp16)(xm_lds[(ITN) * 16 + q * 4 + 2][w] * __builtin_amdgcn_rcpf(ej2)); \
            xj[q * 4 + 3][mp] = (__fp16)(xm_lds[(ITN) * 16 + q * 4 + 3][w] * __builtin_amdgcn_rcpf(ej3)); \
        }                                                                    \
    } while (0)

// ---------------- main ----------------
__global__ __launch_bounds__(1024, 4)
void nomc_main(const float* __restrict__ x_m, const float* __restrict__ x_a,
               const float* __restrict__ Wo, const float* __restrict__ bo,
               const float* __restrict__ Wfc, const float* __restrict__ bfc,
               const void* __restrict__ ws, float* __restrict__ out)
{
    const int b = blockIdx.x, tid = threadIdx.x;
    const int w = tid >> 6, l = tid & 63, q = l >> 4, l15 = l & 15;

    __shared__ __align__(16) __fp16 RT[16][8][64][8];   // 131072 B  RT[t][h>>3][k][(h&7)^((t>>2)<<1)]=e
    __shared__ __align__(16) __fp16 JT[16][64][8];      //  16384 B  JT[t][k][m^((t>>2)<<1)]=e_j
    __shared__ float sinv[16][64];                      //   4096 B  1/rowsum(R)
    __shared__ __align__(16) __fp16 xj[16][8];          //    256 B  [t][m^((t>>2)<<1)]=xm/s_j
    __shared__ __align__(16) __fp16 minL[16][64];       //   2048 B  m_in[t][k]
    __shared__ float xm_lds[T_][M_];                    //   8192 B
    __shared__ float cfin_lds[H_];                      //    256 B
    // total 162304 <= 163840

    {   // stage x_m once
        const float* xmb = x_m + (size_t)b * T_ * M_;
        for (int i = tid; i < T_ * M_; i += 1024) (&xm_lds[0][0])[i] = xmb[i];
    }
    __syncthreads();

    const char* wsb = (const char*)ws;
    const float* wbias = (const float*)(wsb + NTILE * 1024);
    const int sx = q << 1;                   // store-side bank swizzle

    V8 af;                                   // A-frag, persists across barriers
    AF_LOAD(0);
    if (w < 8) J_GROUP(0);                   // prologue J(0)
    __syncthreads();                         // JT(0), xj(0) visible

    float c0 = 0.f, c1 = 0.f, c2 = 0.f, c3 = 0.f;   // c[kt*16 + l15], q-replicated

    for (int it = 0; it < 16; ++it) {
        // ====== m_in(it) at it-top: minL[t][k] = xj[t].JT[t][k] ======
        // JT/xj(it) were written during the previous overlap window
        // (visible since barrier D). minL rides barrier B to the scan.
        {
            V8 jv; jv.v = *(const f16x8*)&JT[w][l][0];
            V8 xv; xv.v = *(const f16x8*)&xj[w][0];
            float s = 0.f;
            s = dot2(jv.p[0], xv.p[0], s);
            s = dot2(jv.p[1], xv.p[1], s);
            s = dot2(jv.p[2], xv.p[2], s);
            s = dot2(jv.p[3], xv.p[3], s);
            minL[w][l] = (__fp16)s;
        }

        // ---- 4 R groups per wave, JIT loads (r21's proven codegen) ----
#pragma unroll 1
        for (int g = 0; g < 4; ++g) {
            const int gg = w * 4 + g;                    // 0..63
            float es0 = 0.f, es1 = 0.f, es2 = 0.f, es3 = 0.f;
            const int hb = gg >> 3, p = (gg & 7) ^ sx;   // swizzled slot
#pragma unroll
            for (int tt = 0; tt < 4; ++tt) {
                const int gt = gg * 4 + tt;
                V8 bf; bf.i = *(const i32x4*)(wsb + (size_t)gt * 1024 + l * 16);
                const float bv = wbias[gt * 16 + l15];
                f32x4 acc = {bv, bv, bv, bv};
                acc = MFMA16(af.v, bf.v, acc);
                const float e0 = EXP2(acc[0]), e1 = EXP2(acc[1]);
                const float e2 = EXP2(acc[2]), e3 = EXP2(acc[3]);
                const int kk = (tt << 4) + l15;
                RT[q * 4 + 0][hb][kk][p] = (__fp16)e0;
                RT[q * 4 + 1][hb][kk][p] = (__fp16)e1;
                RT[q * 4 + 2][hb][kk][p] = (__fp16)e2;
                RT[q * 4 + 3][hb][kk][p] = (__fp16)e3;
                es0 += e0; es1 += e1; es2 += e2; es3 += e3;
            }
            const float sr0 = sum16_all(es0), sr1 = sum16_all(es1);
            const float sr2 = sum16_all(es2), sr3 = sum16_all(es3);
            if (l15 == 0) {
                sinv[q * 4 + 0][gg] = __builtin_amdgcn_rcpf(sr0);
                sinv[q * 4 + 1][gg] = __builtin_amdgcn_rcpf(sr1);
                sinv[q * 4 + 2][gg] = __builtin_amdgcn_rcpf(sr2);
                sinv[q * 4 + 3][gg] = __builtin_amdgcn_rcpf(sr3);
            }
        }
        __syncthreads();   // barrier B: RT, sinv, minL visible

        // ============ scan(it) (wave 15) ∥ J(it+1) (waves 0..7) ============
        if (w == 15) {
            const int ab = q << 5;              // A0 byte base = lane 8q
            for (int u = 0; u < 16; ++u) {
                const int sig = (u >> 2) & 3;   // matches producer swizzle
                // ---- c-independent prefetch (no fences -> compiler pipelines) ----
                const float mi0 = (float)minL[u][l15];
                const float mi1 = (float)minL[u][16 + l15];
                const float mi2 = (float)minL[u][32 + l15];
                const float mi3 = (float)minL[u][48 + l15];
                const float svl = sinv[u][l];
                V8 b00, b01, b10, b11, b20, b21, b30, b31;
                b00.v = *(const f16x8*)&RT[u][q][l15][0];
                b01.v = *(const f16x8*)&RT[u][4 + q][l15][0];
                b10.v = *(const f16x8*)&RT[u][q][16 + l15][0];
                b11.v = *(const f16x8*)&RT[u][4 + q][16 + l15][0];
                b20.v = *(const f16x8*)&RT[u][q][32 + l15][0];
                b21.v = *(const f16x8*)&RT[u][4 + q][32 + l15][0];
                b30.v = *(const f16x8*)&RT[u][q][48 + l15][0];
                b31.v = *(const f16x8*)&RT[u][4 + q][48 + l15][0];
                // ---- chat_l = c[l] * sinv[u][l]  (in-reg, RNE) ----
                const float cown = (q == 0) ? c0 : (q == 1) ? c1 : (q == 2) ? c2 : c3;
                const int spk = pack_pair_rne(cown * svl);  // lane pair 2P,2P+1 -> chat pair P
                // ---- A-frags via bpermute: A0 pair jp <- lane 8q+2(jp^sig);
                //      A1 pair jp <- lane 32+8q+2(jp^sig) (offset 128 folds) ----
                V8 A0f, A1f;
                A0f.i[0] = __builtin_amdgcn_ds_bpermute(ab + ((0 ^ sig) << 3), spk);
                A0f.i[1] = __builtin_amdgcn_ds_bpermute(ab + ((1 ^ sig) << 3), spk);
                A0f.i[2] = __builtin_amdgcn_ds_bpermute(ab + ((2 ^ sig) << 3), spk);
                A0f.i[3] = __builtin_amdgcn_ds_bpermute(ab + ((3 ^ sig) << 3), spk);
                A1f.i[0] = __builtin_amdgcn_ds_bpermute(128 + ab + ((0 ^ sig) << 3), spk);
                A1f.i[1] = __builtin_amdgcn_ds_bpermute(128 + ab + ((1 ^ sig) << 3), spk);
                A1f.i[2] = __builtin_amdgcn_ds_bpermute(128 + ab + ((2 ^ sig) << 3), spk);
                A1f.i[3] = __builtin_amdgcn_ds_bpermute(128 + ab + ((3 ^ sig) << 3), spk);
                // ---- 2-deep MFMA chains, C-init = m_in ----
                f32x4 a0 = {mi0, mi0, mi0, mi0};
                a0 = MFMA16(A0f.v, b00.v, a0);
                a0 = MFMA16(A1f.v, b01.v, a0);
                f32x4 a1 = {mi1, mi1, mi1, mi1};
                a1 = MFMA16(A0f.v, b10.v, a1);
                a1 = MFMA16(A1f.v, b11.v, a1);
                f32x4 a2 = {mi2, mi2, mi2, mi2};
                a2 = MFMA16(A0f.v, b20.v, a2);
                a2 = MFMA16(A1f.v, b21.v, a2);
                f32x4 a3 = {mi3, mi3, mi3, mi3};
                a3 = MFMA16(A0f.v, b30.v, a3);
                a3 = MFMA16(A1f.v, b31.v, a3);
                c0 = a0[0]; c1 = a1[0]; c2 = a2[0]; c3 = a3[0];
            }
            if (it < 15) AF_LOAD(it + 1);
        } else if (it < 15) {
            AF_LOAD(it + 1);                 // af(it+1) for J now, R next it
            if (w < 8) J_GROUP(it + 1);      // JT(it+1) + xj(it+1), hidden
        }
        __syncthreads();   // barrier D
    }

    // ---- epilogue: out = (sigmoid(xa_T@Wo+bo) * c_T) @ Wfc + bfc ----
    if (w == 15) {
        const float cown = (q == 0) ? c0 : (q == 1) ? c1 : (q == 2) ? c2 : c3;
        cfin_lds[l] = cown;                              // all-lane write
        LDS_FENCE();
        const float* xa = x_a + ((size_t)b * T_ + (T_ - 1)) * AUX_;
        float L = bo[l];
#pragma unroll
        for (int a = 0; a < AUX_; ++a) L = fmaf(xa[a], Wo[a * H_ + l], L);
        const float o = 1.0f / (1.0f + __expf(-L));
        const float cfin = cfin_lds[l];
        float p = (o * cfin) * Wfc[l];
        p = sum64_uni(p);
        if (l == 0) out[b] = p + bfc[0];
        out[B_ + b * H_ + l] = cfin;                     // c_final, coalesced
    }
}

} // namespace

extern "C" void kernel_launch(void* const* d_in, const int* in_sizes, int n_in,
                              void* d_out, int out_size, void* d_ws, size_t ws_size,
                              hipStream_t stream) {
    const float* x_m = (const float*)d_in[0];
    const float* x_a = (const float*)d_in[1];
    const float* Wj  = (const float*)d_in[2];
    const float* bj  = (const float*)d_in[3];
    const float* Wr  = (const float*)d_in[4];
    const float* br  = (const float*)d_in[5];
    const float* Wo  = (const float*)d_in[6];
    const float* bo  = (const float*)d_in[7];
    const float* Wfc = (const float*)d_in[8];
    const float* bfc = (const float*)d_in[9];
    float* out = (float*)d_out;

    hipLaunchKernelGGL(nomc_prep, dim3(NTILE), dim3(64), 0, stream,
                       Wj, bj, Wr, br, d_ws);
    hipLaunchKernelGGL(nomc_main, dim3(B_), dim3(1024), 0, stream,
                       x_m, x_a, Wo, bo, Wfc, bfc, d_ws, out);
}